// Round 14
// baseline (178.800 us; speedup 1.0000x reference)
//
#include <hip/hip_runtime.h>
#include <math.h>

#define NG 64
#define HID 64
#define ELL 64      // slots per node; P(deg>64)~1e-19 for Poisson(16)
#define BCAP 110592 // per-bucket capacity (mean ~E/8=100k, generous slack)

typedef __attribute__((ext_vector_type(8))) short bf16x8;
typedef __attribute__((ext_vector_type(4))) float f32x4;

// RNE f32 -> bf16 bit helpers (data finite; no NaN handling needed)
__device__ __forceinline__ unsigned int bfbits(float f) {
    unsigned int u = __float_as_uint(f);
    return (u + 0x7FFFu + ((u >> 16) & 1u)) >> 16;
}
__device__ __forceinline__ float bfval(unsigned int bits) {
    return __uint_as_float(bits << 16);
}

// ---- zero deg + bucket counters ----
__global__ void k_zero0(int4* __restrict__ deg4, int4* __restrict__ gc4, int n4) {
    int i = blockIdx.x * blockDim.x + threadIdx.x;
    if (i < n4) deg4[i] = make_int4(0, 0, 0, 0);
    if (i < 2) gc4[i] = make_int4(0, 0, 0, 0);
}

// ---- Pass A: bin edges by dst-range (8 buckets) + W pre-split (tail blocks) ----
__global__ __launch_bounds__(256) void k_binA(const int* __restrict__ src,
                                              const int* __restrict__ dst,
                                              int E, unsigned MAGIC,
                                              int2* __restrict__ binned,
                                              int* __restrict__ gcount, int nbin,
                                              const float* __restrict__ W1,
                                              const float* __restrict__ W2,
                                              unsigned short* __restrict__ W1hi,
                                              unsigned short* __restrict__ W1lo,
                                              unsigned short* __restrict__ W2hi,
                                              unsigned short* __restrict__ W2lo) {
    const int t = threadIdx.x;
    if (blockIdx.x >= nbin) {  // W-conversion blocks
        int idx = (blockIdx.x - nbin) * 256 + t;
        if (idx < 128 * 64) {
            int k = idx >> 6, c = idx & 63;
            float f = W1[idx];
            unsigned hb = bfbits(f);
            W1hi[c * 128 + k] = (unsigned short)hb;
            W1lo[c * 128 + k] = (unsigned short)bfbits(f - bfval(hb));
        } else if (idx < 128 * 64 + 64 * 64) {
            int i2 = idx - 128 * 64;
            int k = i2 >> 6, c = i2 & 63;
            float f = W2[i2];
            unsigned hb = bfbits(f);
            W2hi[c * 64 + k] = (unsigned short)hb;
            W2lo[c * 64 + k] = (unsigned short)bfbits(f - bfval(hb));
        }
        return;
    }
    __shared__ int cnt[8], base[8];
    if (t < 8) cnt[t] = 0;
    __syncthreads();
    int e = blockIdx.x * 256 + t;
    int s = 0, d = 0, b = 0, rk = 0;
    bool val = (e < E);
    if (val) {
        s = src[e]; d = dst[e];
        b = __umulhi((unsigned)d, MAGIC);
        rk = atomicAdd(&cnt[b], 1);
    }
    __syncthreads();
    if (t < 8) base[t] = (cnt[t] > 0) ? atomicAdd(&gcount[t], cnt[t]) : 0;
    __syncthreads();
    if (val) {
        int off = base[b] + rk;
        if (off < BCAP) binned[(size_t)b * BCAP + off] = make_int2(s, d);
    }
}

// ---- Pass B: XCD-affine scatter. Block j -> bucket j%8 (round-robin XCD). ----
__global__ __launch_bounds__(256) void k_binB(const int2* __restrict__ binned,
                                              const int* __restrict__ gcount,
                                              int* __restrict__ deg,
                                              int* __restrict__ col_ell) {
    const int r = blockIdx.x & 7, c = blockIdx.x >> 3;
    const int t = threadIdx.x;
    const int count = min(gcount[r], BCAP);
    const int2* bb = binned + (size_t)r * BCAP;
#pragma unroll
    for (int k = 0; k < 8; ++k) {
        int idx = c * 2048 + k * 256 + t;
        if (idx < count) {
            int2 sd = bb[idx];
            int slot = atomicAdd(deg + sd.y, 1);
            if (slot < ELL) col_ell[(size_t)sd.y * ELL + slot] = sd.x;
        }
    }
}

// ---- aux: dinv + graph boundaries (sorted batch) ----
__global__ __launch_bounds__(256) void k_aux(const int* __restrict__ deg,
                                             const int* __restrict__ batch,
                                             float* __restrict__ dinv,
                                             int* __restrict__ gstart, int n) {
    int i = blockIdx.x * 256 + threadIdx.x;
    if (i < n) {
        dinv[i] = 1.0f / sqrtf((float)deg[i] + 1.0f);
        int bi = batch[i];
        int bp = (i == 0) ? -1 : batch[i - 1];
        for (int g = bp + 1; g <= bi; ++g) gstart[g] = i;
        if (i == n - 1)
            for (int g = bi + 1; g <= NG; ++g) gstart[g] = n;
    }
}

// ---- MFMA GEMM (layer 1): out = (A[n,128] @ W) * dinv[row], 32 rows/wave ----
template<int K>
__global__ __launch_bounds__(256) void k_gemm_mfma(const float* __restrict__ A,
                                                   const unsigned short* __restrict__ Whi,
                                                   const unsigned short* __restrict__ Wlo,
                                                   const float* __restrict__ dinv,
                                                   float* __restrict__ out, int n) {
    const int wave = threadIdx.x >> 6, lane = threadIdx.x & 63;
    const int ntile2 = (n + 31) >> 5;
    const int tile2 = blockIdx.x * 4 + wave;
    if (tile2 >= ntile2) return;
    const int lrow = lane & 15;
    const int kgrp = lane >> 4;
    const int r0 = tile2 * 32 + lrow;
    const int r1 = r0 + 16;

    f32x4 acc0[4], acc1[4];
#pragma unroll
    for (int ct = 0; ct < 4; ++ct) {
        acc0[ct] = (f32x4){0.f, 0.f, 0.f, 0.f};
        acc1[ct] = (f32x4){0.f, 0.f, 0.f, 0.f};
    }

#pragma unroll
    for (int s = 0; s < K / 32; ++s) {
        float a0[8], a1[8];
        {
            const float* p0 = A + (size_t)r0 * K + s * 32 + kgrp * 8;
            const float* p1 = A + (size_t)r1 * K + s * 32 + kgrp * 8;
            float4 u0, u1, w0, w1;
            if (r0 < n) { u0 = *(const float4*)p0; u1 = *(const float4*)(p0 + 4); }
            else { u0 = make_float4(0.f,0.f,0.f,0.f); u1 = u0; }
            if (r1 < n) { w0 = *(const float4*)p1; w1 = *(const float4*)(p1 + 4); }
            else { w0 = make_float4(0.f,0.f,0.f,0.f); w1 = w0; }
            a0[0]=u0.x; a0[1]=u0.y; a0[2]=u0.z; a0[3]=u0.w;
            a0[4]=u1.x; a0[5]=u1.y; a0[6]=u1.z; a0[7]=u1.w;
            a1[0]=w0.x; a1[1]=w0.y; a1[2]=w0.z; a1[3]=w0.w;
            a1[4]=w1.x; a1[5]=w1.y; a1[6]=w1.z; a1[7]=w1.w;
        }
        bf16x8 ahi0, alo0, ahi1, alo1;
#pragma unroll
        for (int e = 0; e < 8; ++e) {
            unsigned hb0 = bfbits(a0[e]);
            ahi0[e] = (short)hb0;
            alo0[e] = (short)bfbits(a0[e] - bfval(hb0));
            unsigned hb1 = bfbits(a1[e]);
            ahi1[e] = (short)hb1;
            alo1[e] = (short)bfbits(a1[e] - bfval(hb1));
        }
#pragma unroll
        for (int ct = 0; ct < 4; ++ct) {
            const size_t wo = (size_t)(ct * 16 + lrow) * K + s * 32 + kgrp * 8;
            bf16x8 whi = *(const bf16x8*)(Whi + wo);
            bf16x8 wlo = *(const bf16x8*)(Wlo + wo);
            acc0[ct] = __builtin_amdgcn_mfma_f32_16x16x32_bf16(ahi0, whi, acc0[ct], 0, 0, 0);
            acc0[ct] = __builtin_amdgcn_mfma_f32_16x16x32_bf16(alo0, whi, acc0[ct], 0, 0, 0);
            acc0[ct] = __builtin_amdgcn_mfma_f32_16x16x32_bf16(ahi0, wlo, acc0[ct], 0, 0, 0);
            acc1[ct] = __builtin_amdgcn_mfma_f32_16x16x32_bf16(ahi1, whi, acc1[ct], 0, 0, 0);
            acc1[ct] = __builtin_amdgcn_mfma_f32_16x16x32_bf16(alo1, whi, acc1[ct], 0, 0, 0);
            acc1[ct] = __builtin_amdgcn_mfma_f32_16x16x32_bf16(ahi1, wlo, acc1[ct], 0, 0, 0);
        }
    }

#pragma unroll
    for (int r = 0; r < 4; ++r) {
        int o0 = tile2 * 32 + kgrp * 4 + r;
        if (o0 < n) {
            float dv = dinv[o0];
#pragma unroll
            for (int ct = 0; ct < 4; ++ct)
                out[(size_t)o0 * HID + ct * 16 + lrow] = acc0[ct][r] * dv;
        }
        int o1 = o0 + 16;
        if (o1 < n) {
            float dv = dinv[o1];
#pragma unroll
            for (int ct = 0; ct < 4; ++ct)
                out[(size_t)o1 * HID + ct * 16 + lrow] = acc1[ct][r] * dv;
        }
    }
}

// ---- FUSED: lane-group ELL gather (float4 rows, 32 fetches in flight/wave)
//      + gemm layer-2 (MFMA from 32-row LDS tile). ----
__global__ __launch_bounds__(512) void k_gather_gemm2(const float* __restrict__ hs,
                                                      const int* __restrict__ deg,
                                                      const int* __restrict__ col_ell,
                                                      const float* __restrict__ dinv,
                                                      const float* __restrict__ bias,
                                                      const unsigned short* __restrict__ Whi,
                                                      const unsigned short* __restrict__ Wlo,
                                                      float* __restrict__ outB, int n) {
    __shared__ float Ash[32][68];  // +4 pad for MFMA-phase b128 reads
    const int wave = threadIdx.x >> 6, lane = threadIdx.x & 63;
    const int grp = lane >> 4, sub = lane & 15;
    const int row = wave * 4 + grp;
    const int node = blockIdx.x * 32 + row;
    const bool has = node < n;

    float4 acc = make_float4(0.f, 0.f, 0.f, 0.f);
    float di = 0.f;
    int j = 0, e = 0;
    const int* cbase = col_ell + (size_t)node * ELL;
    if (has) {
        e = min(deg[node], ELL);
        di = dinv[node];
        acc = *(const float4*)(hs + (size_t)node * HID + sub * 4);
    }
    while (__any(j < e)) {
        int cc[8];
#pragma unroll
        for (int t = 0; t < 8; ++t) cc[t] = (j + t < e) ? cbase[j + t] : -1;
        float4 vv[8];
#pragma unroll
        for (int t = 0; t < 8; ++t)
            if (cc[t] >= 0) vv[t] = *(const float4*)(hs + (size_t)cc[t] * HID + sub * 4);
#pragma unroll
        for (int t = 0; t < 8; ++t)
            if (cc[t] >= 0) {
                acc.x += vv[t].x; acc.y += vv[t].y;
                acc.z += vv[t].z; acc.w += vv[t].w;
            }
        j += 8;
    }
    {
        float4 bv = *(const float4*)(bias + sub * 4);
        float4 o;
        o.x = has ? fmaxf(fmaf(acc.x, di, bv.x), 0.f) : 0.f;
        o.y = has ? fmaxf(fmaf(acc.y, di, bv.y), 0.f) : 0.f;
        o.z = has ? fmaxf(fmaf(acc.z, di, bv.z), 0.f) : 0.f;
        o.w = has ? fmaxf(fmaf(acc.w, di, bv.w), 0.f) : 0.f;
        *(float4*)&Ash[row][sub * 4] = o;
    }
    __syncthreads();

    // gemm phase (K=64): 8 units (2 rowtiles x 4 coltiles), 1 per wave
    const int rt = wave >> 2, ct = wave & 3;
    const int lrow = lane & 15;
    const int kgrp = lane >> 4;
    f32x4 a = (f32x4){0.f, 0.f, 0.f, 0.f};
#pragma unroll
    for (int s = 0; s < 2; ++s) {
        const float* ap = &Ash[rt * 16 + lrow][s * 32 + kgrp * 8];
        float4 u0 = *(const float4*)ap;
        float4 u1 = *(const float4*)(ap + 4);
        float av[8] = {u0.x, u0.y, u0.z, u0.w, u1.x, u1.y, u1.z, u1.w};
        bf16x8 ahi, alo;
#pragma unroll
        for (int e2 = 0; e2 < 8; ++e2) {
            unsigned hb = bfbits(av[e2]);
            ahi[e2] = (short)hb;
            alo[e2] = (short)bfbits(av[e2] - bfval(hb));
        }
        const size_t wo = (size_t)(ct * 16 + lrow) * 64 + s * 32 + kgrp * 8;
        bf16x8 whi = *(const bf16x8*)(Whi + wo);
        bf16x8 wlo = *(const bf16x8*)(Wlo + wo);
        a = __builtin_amdgcn_mfma_f32_16x16x32_bf16(ahi, whi, a, 0, 0, 0);
        a = __builtin_amdgcn_mfma_f32_16x16x32_bf16(alo, whi, a, 0, 0, 0);
        a = __builtin_amdgcn_mfma_f32_16x16x32_bf16(ahi, wlo, a, 0, 0, 0);
    }
#pragma unroll
    for (int r = 0; r < 4; ++r) {
        int orow = blockIdx.x * 32 + rt * 16 + kgrp * 4 + r;
        if (orow < n)
            outB[(size_t)orow * HID + ct * 16 + lrow] = a[r] * dinv[orow];
    }
}

// ---- lane-group ELL gather (layer 2), direct store ----
__global__ __launch_bounds__(256) void k_gather(const float* __restrict__ hs,
                                                const int* __restrict__ deg,
                                                const int* __restrict__ col_ell,
                                                const float* __restrict__ dinv,
                                                const float* __restrict__ bias,
                                                float* __restrict__ out, int n) {
    const int wave = threadIdx.x >> 6, lane = threadIdx.x & 63;
    const int grp = lane >> 4, sub = lane & 15;
    const int node = blockIdx.x * 16 + wave * 4 + grp;
    const bool has = node < n;

    float4 acc = make_float4(0.f, 0.f, 0.f, 0.f);
    float di = 0.f;
    int j = 0, e = 0;
    const int* cbase = col_ell + (size_t)node * ELL;
    if (has) {
        e = min(deg[node], ELL);
        di = dinv[node];
        acc = *(const float4*)(hs + (size_t)node * HID + sub * 4);
    }
    while (__any(j < e)) {
        int cc[8];
#pragma unroll
        for (int t = 0; t < 8; ++t) cc[t] = (j + t < e) ? cbase[j + t] : -1;
        float4 vv[8];
#pragma unroll
        for (int t = 0; t < 8; ++t)
            if (cc[t] >= 0) vv[t] = *(const float4*)(hs + (size_t)cc[t] * HID + sub * 4);
#pragma unroll
        for (int t = 0; t < 8; ++t)
            if (cc[t] >= 0) {
                acc.x += vv[t].x; acc.y += vv[t].y;
                acc.z += vv[t].z; acc.w += vv[t].w;
            }
        j += 8;
    }
    if (has) {
        float4 bv = *(const float4*)(bias + sub * 4);
        float4 o;
        o.x = fmaxf(fmaf(acc.x, di, bv.x), 0.f);
        o.y = fmaxf(fmaf(acc.y, di, bv.y), 0.f);
        o.z = fmaxf(fmaf(acc.z, di, bv.z), 0.f);
        o.w = fmaxf(fmaf(acc.w, di, bv.w), 0.f);
        *(float4*)(out + (size_t)node * HID + sub * 4) = o;
    }
}

// ---- fused mean-pool + MLP head ----
__global__ __launch_bounds__(512) void k_poolhead(const float* __restrict__ h,
                                                  const int* __restrict__ gstart,
                                                  const float* __restrict__ Wc1,
                                                  const float* __restrict__ bc1,
                                                  const float* __restrict__ Wc2,
                                                  const float* __restrict__ bc2,
                                                  float* __restrict__ outp, int n) {
    const int g = blockIdx.x;
    const int lo = gstart[g], lo2 = gstart[g + 1];
    const int t = threadIdx.x;
    const int rg = t >> 4;
    const int c4 = (t & 15) * 4;
    float4 acc = make_float4(0.f, 0.f, 0.f, 0.f);
    for (int r = lo + rg; r < lo2; r += 32) {
        float4 v = *(const float4*)(h + (size_t)r * HID + c4);
        acc.x += v.x; acc.y += v.y; acc.z += v.z; acc.w += v.w;
    }
    __shared__ float4 red[32][16];
    __shared__ float gmv[HID];
    __shared__ float zs[32];
    red[rg][t & 15] = acc;
    __syncthreads();
    if (t < 16) {
        float4 s = red[0][t];
#pragma unroll
        for (int g2 = 1; g2 < 32; ++g2) {
            float4 v = red[g2][t];
            s.x += v.x; s.y += v.y; s.z += v.z; s.w += v.w;
        }
        float inv = 1.0f / fmaxf((float)(lo2 - lo), 1.0f);
        gmv[t * 4 + 0] = s.x * inv; gmv[t * 4 + 1] = s.y * inv;
        gmv[t * 4 + 2] = s.z * inv; gmv[t * 4 + 3] = s.w * inv;
    }
    __syncthreads();
    if (t < 32) {
        float z = bc1[t];
#pragma unroll 8
        for (int k = 0; k < HID; ++k) z = fmaf(gmv[k], Wc1[k * 32 + t], z);
        zs[t] = fmaxf(z, 0.f) * Wc2[t];
    }
    __syncthreads();
    if (t == 0) {
        float o = bc2[0];
#pragma unroll
        for (int j = 0; j < 32; ++j) o += zs[j];
        outp[g] = o;
    }
}

extern "C" void kernel_launch(void* const* d_in, const int* in_sizes, int n_in,
                              void* d_out, int out_size, void* d_ws, size_t ws_size,
                              hipStream_t stream) {
    const float* x    = (const float*)d_in[0];
    const int*   ei   = (const int*)d_in[1];
    const int*   batch= (const int*)d_in[2];
    const float* W1   = (const float*)d_in[3];
    const float* b1   = (const float*)d_in[4];
    const float* W2   = (const float*)d_in[5];
    const float* b2   = (const float*)d_in[6];
    const float* Wc1  = (const float*)d_in[7];
    const float* bc1  = (const float*)d_in[8];
    const float* Wc2  = (const float*)d_in[9];
    const float* bc2  = (const float*)d_in[10];

    const int E = in_sizes[1] / 2;
    const int n = in_sizes[0] / 128;   // 50000 nodes
    const int* srcp = ei;
    const int* dstp = ei + E;

    char* ws = (char*)d_ws;
    auto alloc = [&](size_t bytes) {
        char* p = ws;
        ws += (bytes + 255) & ~(size_t)255;
        return p;
    };
    int*   deg      = (int*)  alloc((size_t)((n + 3) & ~3) * 4);
    int*   gcount   = (int*)  alloc(8 * 4);
    float* dinv     = (float*)alloc((size_t)n * 4);
    int*   gstart   = (int*)  alloc((size_t)(NG + 1) * 4);
    int*   col_ell  = (int*)  alloc((size_t)n * ELL * 4);
    int2*  binned   = (int2*) alloc((size_t)8 * BCAP * 8);
    float* bufA     = (float*)alloc((size_t)n * HID * 4);
    float* bufB     = (float*)alloc((size_t)n * HID * 4);
    unsigned short* W1hi = (unsigned short*)alloc(128 * 64 * 2);
    unsigned short* W1lo = (unsigned short*)alloc(128 * 64 * 2);
    unsigned short* W2hi = (unsigned short*)alloc(64 * 64 * 2);
    unsigned short* W2lo = (unsigned short*)alloc(64 * 64 * 2);

    const int n4 = (n + 3) / 4;
    k_zero0<<<(n4 + 255) / 256, 256, 0, stream>>>((int4*)deg, (int4*)gcount, n4);

    const unsigned MAGIC = (unsigned)((((unsigned long long)8) << 32) / (unsigned)n) + 1u;
    const int nbin = (E + 255) / 256;
    const int wblk = (128 * 64 + 64 * 64 + 255) / 256;

    // Pass A: bin by dst-range (+ W pre-split in tail blocks)
    k_binA<<<nbin + wblk, 256, 0, stream>>>(srcp, dstp, E, MAGIC, binned, gcount, nbin,
                                            W1, W2, W1hi, W1lo, W2hi, W2lo);
    // Pass B: XCD-affine ELL scatter
    const int KB = (BCAP + 2047) / 2048;
    k_binB<<<8 * KB, 256, 0, stream>>>(binned, gcount, deg, col_ell);

    const int nblk = (n + 255) / 256;
    k_aux<<<nblk, 256, 0, stream>>>(deg, batch, dinv, gstart, n);

    const int mblocks = ((n + 31) / 32 + 3) / 4;

    // Layer 1 GEMM, then fused {gather1 + layer-2 GEMM}, then gather2
    k_gemm_mfma<128><<<mblocks, 256, 0, stream>>>(x, W1hi, W1lo, dinv, bufA, n);
    k_gather_gemm2<<<(n + 31) / 32, 512, 0, stream>>>(bufA, deg, col_ell, dinv, b1,
                                                      W2hi, W2lo, bufB, n);
    k_gather<<<(n + 15) / 16, 256, 0, stream>>>(bufB, deg, col_ell, dinv, b2, bufA, n);

    // Fused pool + head
    k_poolhead<<<NG, 512, 0, stream>>>(bufA, gstart, Wc1, bc1, Wc2, bc2, (float*)d_out, n);
}

// Round 15
// 161.730 us; speedup vs baseline: 1.1055x; 1.1055x over previous
//
#include <hip/hip_runtime.h>
#include <math.h>

#define NG 64
#define HID 64
#define ELL 64  // slots per node; P(deg>64)~1e-19 for Poisson(16)

typedef __attribute__((ext_vector_type(8))) short bf16x8;
typedef __attribute__((ext_vector_type(4))) float f32x4;

// RNE f32 -> bf16 bit helpers (data finite; no NaN handling needed)
__device__ __forceinline__ unsigned int bfbits(float f) {
    unsigned int u = __float_as_uint(f);
    return (u + 0x7FFFu + ((u >> 16) & 1u)) >> 16;
}
__device__ __forceinline__ float bfval(unsigned int bits) {
    return __uint_as_float(bits << 16);
}

// ---- zero deg + W pre-split (one small kernel) ----
__global__ void k_prep(int4* __restrict__ deg4, int n4,
                       const float* __restrict__ W1, const float* __restrict__ W2,
                       unsigned short* __restrict__ W1hi, unsigned short* __restrict__ W1lo,
                       unsigned short* __restrict__ W2hi, unsigned short* __restrict__ W2lo) {
    int i = blockIdx.x * blockDim.x + threadIdx.x;
    if (i < n4) deg4[i] = make_int4(0, 0, 0, 0);
    if (i < 128 * 64) {
        int k = i >> 6, c = i & 63;
        float f = W1[i];
        unsigned hb = bfbits(f);
        W1hi[c * 128 + k] = (unsigned short)hb;
        W1lo[c * 128 + k] = (unsigned short)bfbits(f - bfval(hb));
    }
    int i2 = i - 128 * 64;
    if (i2 >= 0 && i2 < 64 * 64) {
        int k = i2 >> 6, c = i2 & 63;
        float f = W2[i2];
        unsigned hb = bfbits(f);
        W2hi[c * 64 + k] = (unsigned short)hb;
        W2lo[c * 64 + k] = (unsigned short)bfbits(f - bfval(hb));
    }
}

// ---- MEGA: {ELL build} U {gemm1 unscaled} U {gstart} by block range ----
// degfill blocks stall on random scatter; gemm blocks fill the idle issue slots.
__global__ __launch_bounds__(256) void k_mega(const int* __restrict__ src,
                                              const int* __restrict__ dst, int E,
                                              int* __restrict__ deg,
                                              int* __restrict__ col_ell,
                                              const float* __restrict__ A,   // x [n,128]
                                              const unsigned short* __restrict__ Whi,
                                              const unsigned short* __restrict__ Wlo,
                                              float* __restrict__ out,       // h [n,64]
                                              const int* __restrict__ batch,
                                              int* __restrict__ gstart,
                                              int n, int nbin, int mblocks) {
    const int bid = blockIdx.x;
    const int t = threadIdx.x;

    if (bid < nbin) {  // ---- ELL build ----
        int e = bid * 256 + t;
        if (e < E) {
            int d = dst[e];
            int slot = atomicAdd(deg + d, 1);
            if (slot < ELL) col_ell[(size_t)d * ELL + slot] = src[e];
        }
        return;
    }
    if (bid >= nbin + mblocks) {  // ---- gstart (sorted batch boundaries) ----
        int i = (bid - nbin - mblocks) * 256 + t;
        if (i < n) {
            int bi = batch[i];
            int bp = (i == 0) ? -1 : batch[i - 1];
            for (int g = bp + 1; g <= bi; ++g) gstart[g] = i;
            if (i == n - 1)
                for (int g = bi + 1; g <= NG; ++g) gstart[g] = n;
        }
        return;
    }

    // ---- gemm1 (K=128): out = A @ W1 (UNSCALED; dinv applied downstream) ----
    constexpr int K = 128;
    const int wave = t >> 6, lane = t & 63;
    const int ntile2 = (n + 31) >> 5;
    const int tile2 = (bid - nbin) * 4 + wave;
    if (tile2 >= ntile2) return;
    const int lrow = lane & 15;
    const int kgrp = lane >> 4;
    const int r0 = tile2 * 32 + lrow;
    const int r1 = r0 + 16;

    f32x4 acc0[4], acc1[4];
#pragma unroll
    for (int ct = 0; ct < 4; ++ct) {
        acc0[ct] = (f32x4){0.f, 0.f, 0.f, 0.f};
        acc1[ct] = (f32x4){0.f, 0.f, 0.f, 0.f};
    }

#pragma unroll
    for (int s = 0; s < K / 32; ++s) {
        float a0[8], a1[8];
        {
            const float* p0 = A + (size_t)r0 * K + s * 32 + kgrp * 8;
            const float* p1 = A + (size_t)r1 * K + s * 32 + kgrp * 8;
            float4 u0, u1, w0, w1;
            if (r0 < n) { u0 = *(const float4*)p0; u1 = *(const float4*)(p0 + 4); }
            else { u0 = make_float4(0.f,0.f,0.f,0.f); u1 = u0; }
            if (r1 < n) { w0 = *(const float4*)p1; w1 = *(const float4*)(p1 + 4); }
            else { w0 = make_float4(0.f,0.f,0.f,0.f); w1 = w0; }
            a0[0]=u0.x; a0[1]=u0.y; a0[2]=u0.z; a0[3]=u0.w;
            a0[4]=u1.x; a0[5]=u1.y; a0[6]=u1.z; a0[7]=u1.w;
            a1[0]=w0.x; a1[1]=w0.y; a1[2]=w0.z; a1[3]=w0.w;
            a1[4]=w1.x; a1[5]=w1.y; a1[6]=w1.z; a1[7]=w1.w;
        }
        bf16x8 ahi0, alo0, ahi1, alo1;
#pragma unroll
        for (int e = 0; e < 8; ++e) {
            unsigned hb0 = bfbits(a0[e]);
            ahi0[e] = (short)hb0;
            alo0[e] = (short)bfbits(a0[e] - bfval(hb0));
            unsigned hb1 = bfbits(a1[e]);
            ahi1[e] = (short)hb1;
            alo1[e] = (short)bfbits(a1[e] - bfval(hb1));
        }
#pragma unroll
        for (int ct = 0; ct < 4; ++ct) {
            const size_t wo = (size_t)(ct * 16 + lrow) * K + s * 32 + kgrp * 8;
            bf16x8 whi = *(const bf16x8*)(Whi + wo);
            bf16x8 wlo = *(const bf16x8*)(Wlo + wo);
            acc0[ct] = __builtin_amdgcn_mfma_f32_16x16x32_bf16(ahi0, whi, acc0[ct], 0, 0, 0);
            acc0[ct] = __builtin_amdgcn_mfma_f32_16x16x32_bf16(alo0, whi, acc0[ct], 0, 0, 0);
            acc0[ct] = __builtin_amdgcn_mfma_f32_16x16x32_bf16(ahi0, wlo, acc0[ct], 0, 0, 0);
            acc1[ct] = __builtin_amdgcn_mfma_f32_16x16x32_bf16(ahi1, whi, acc1[ct], 0, 0, 0);
            acc1[ct] = __builtin_amdgcn_mfma_f32_16x16x32_bf16(alo1, whi, acc1[ct], 0, 0, 0);
            acc1[ct] = __builtin_amdgcn_mfma_f32_16x16x32_bf16(ahi1, wlo, acc1[ct], 0, 0, 0);
        }
    }

#pragma unroll
    for (int r = 0; r < 4; ++r) {
        int o0 = tile2 * 32 + kgrp * 4 + r;
        if (o0 < n) {
#pragma unroll
            for (int ct = 0; ct < 4; ++ct)
                out[(size_t)o0 * HID + ct * 16 + lrow] = acc0[ct][r];
        }
        int o1 = o0 + 16;
        if (o1 < n) {
#pragma unroll
            for (int ct = 0; ct < 4; ++ct)
                out[(size_t)o1 * HID + ct * 16 + lrow] = acc1[ct][r];
        }
    }
}

// ---- dinv only (deg complete) ----
__global__ void k_dinv(const int* __restrict__ deg, float* __restrict__ dinv, int n) {
    int i = blockIdx.x * blockDim.x + threadIdx.x;
    if (i < n) dinv[i] = 1.0f / sqrtf((float)deg[i] + 1.0f);
}

// ---- FUSED: lane-group ELL gather (h unscaled -> per-edge dinv) + gemm2 ----
__global__ __launch_bounds__(512) void k_gather_gemm2(const float* __restrict__ h,
                                                      const int* __restrict__ deg,
                                                      const int* __restrict__ col_ell,
                                                      const float* __restrict__ dinv,
                                                      const float* __restrict__ bias,
                                                      const unsigned short* __restrict__ Whi,
                                                      const unsigned short* __restrict__ Wlo,
                                                      float* __restrict__ outB, int n) {
    __shared__ float Ash[32][68];  // +4 pad for MFMA-phase b128 reads
    const int wave = threadIdx.x >> 6, lane = threadIdx.x & 63;
    const int grp = lane >> 4, sub = lane & 15;
    const int row = wave * 4 + grp;
    const int node = blockIdx.x * 32 + row;
    const bool has = node < n;

    float4 acc = make_float4(0.f, 0.f, 0.f, 0.f);
    float di = 0.f;
    int j = 0, e = 0;
    const int* cbase = col_ell + (size_t)node * ELL;
    if (has) {
        e = min(deg[node], ELL);
        di = dinv[node];
        float4 hv = *(const float4*)(h + (size_t)node * HID + sub * 4);
        acc.x = hv.x * di; acc.y = hv.y * di;
        acc.z = hv.z * di; acc.w = hv.w * di;
    }
    while (__any(j < e)) {
        int cc[8];
#pragma unroll
        for (int t = 0; t < 8; ++t) cc[t] = (j + t < e) ? cbase[j + t] : -1;
        float4 vv[8];
        float dv[8];
#pragma unroll
        for (int t = 0; t < 8; ++t)
            if (cc[t] >= 0) {
                vv[t] = *(const float4*)(h + (size_t)cc[t] * HID + sub * 4);
                dv[t] = dinv[cc[t]];
            }
#pragma unroll
        for (int t = 0; t < 8; ++t)
            if (cc[t] >= 0) {
                acc.x = fmaf(vv[t].x, dv[t], acc.x);
                acc.y = fmaf(vv[t].y, dv[t], acc.y);
                acc.z = fmaf(vv[t].z, dv[t], acc.z);
                acc.w = fmaf(vv[t].w, dv[t], acc.w);
            }
        j += 8;
    }
    {
        float4 bv = *(const float4*)(bias + sub * 4);
        float4 o;
        o.x = has ? fmaxf(fmaf(acc.x, di, bv.x), 0.f) : 0.f;
        o.y = has ? fmaxf(fmaf(acc.y, di, bv.y), 0.f) : 0.f;
        o.z = has ? fmaxf(fmaf(acc.z, di, bv.z), 0.f) : 0.f;
        o.w = has ? fmaxf(fmaf(acc.w, di, bv.w), 0.f) : 0.f;
        *(float4*)&Ash[row][sub * 4] = o;
    }
    __syncthreads();

    // gemm phase (K=64): 8 units (2 rowtiles x 4 coltiles), 1 per wave;
    // output pre-scaled by dinv so gather2 runs the cheap pre-scaled form.
    const int rt = wave >> 2, ct = wave & 3;
    const int lrow = lane & 15;
    const int kgrp = lane >> 4;
    f32x4 a = (f32x4){0.f, 0.f, 0.f, 0.f};
#pragma unroll
    for (int s = 0; s < 2; ++s) {
        const float* ap = &Ash[rt * 16 + lrow][s * 32 + kgrp * 8];
        float4 u0 = *(const float4*)ap;
        float4 u1 = *(const float4*)(ap + 4);
        float av[8] = {u0.x, u0.y, u0.z, u0.w, u1.x, u1.y, u1.z, u1.w};
        bf16x8 ahi, alo;
#pragma unroll
        for (int e2 = 0; e2 < 8; ++e2) {
            unsigned hb = bfbits(av[e2]);
            ahi[e2] = (short)hb;
            alo[e2] = (short)bfbits(av[e2] - bfval(hb));
        }
        const size_t wo = (size_t)(ct * 16 + lrow) * 64 + s * 32 + kgrp * 8;
        bf16x8 whi = *(const bf16x8*)(Whi + wo);
        bf16x8 wlo = *(const bf16x8*)(Wlo + wo);
        a = __builtin_amdgcn_mfma_f32_16x16x32_bf16(ahi, whi, a, 0, 0, 0);
        a = __builtin_amdgcn_mfma_f32_16x16x32_bf16(alo, whi, a, 0, 0, 0);
        a = __builtin_amdgcn_mfma_f32_16x16x32_bf16(ahi, wlo, a, 0, 0, 0);
    }
#pragma unroll
    for (int r = 0; r < 4; ++r) {
        int orow = blockIdx.x * 32 + rt * 16 + kgrp * 4 + r;
        if (orow < n)
            outB[(size_t)orow * HID + ct * 16 + lrow] = a[r] * dinv[orow];
    }
}

// ---- lane-group ELL gather (layer 2, hs pre-scaled), direct store ----
__global__ __launch_bounds__(256) void k_gather(const float* __restrict__ hs,
                                                const int* __restrict__ deg,
                                                const int* __restrict__ col_ell,
                                                const float* __restrict__ dinv,
                                                const float* __restrict__ bias,
                                                float* __restrict__ out, int n) {
    const int wave = threadIdx.x >> 6, lane = threadIdx.x & 63;
    const int grp = lane >> 4, sub = lane & 15;
    const int node = blockIdx.x * 16 + wave * 4 + grp;
    const bool has = node < n;

    float4 acc = make_float4(0.f, 0.f, 0.f, 0.f);
    float di = 0.f;
    int j = 0, e = 0;
    const int* cbase = col_ell + (size_t)node * ELL;
    if (has) {
        e = min(deg[node], ELL);
        di = dinv[node];
        acc = *(const float4*)(hs + (size_t)node * HID + sub * 4);
    }
    while (__any(j < e)) {
        int cc[8];
#pragma unroll
        for (int t = 0; t < 8; ++t) cc[t] = (j + t < e) ? cbase[j + t] : -1;
        float4 vv[8];
#pragma unroll
        for (int t = 0; t < 8; ++t)
            if (cc[t] >= 0) vv[t] = *(const float4*)(hs + (size_t)cc[t] * HID + sub * 4);
#pragma unroll
        for (int t = 0; t < 8; ++t)
            if (cc[t] >= 0) {
                acc.x += vv[t].x; acc.y += vv[t].y;
                acc.z += vv[t].z; acc.w += vv[t].w;
            }
        j += 8;
    }
    if (has) {
        float4 bv = *(const float4*)(bias + sub * 4);
        float4 o;
        o.x = fmaxf(fmaf(acc.x, di, bv.x), 0.f);
        o.y = fmaxf(fmaf(acc.y, di, bv.y), 0.f);
        o.z = fmaxf(fmaf(acc.z, di, bv.z), 0.f);
        o.w = fmaxf(fmaf(acc.w, di, bv.w), 0.f);
        *(float4*)(out + (size_t)node * HID + sub * 4) = o;
    }
}

// ---- fused mean-pool + MLP head ----
__global__ __launch_bounds__(512) void k_poolhead(const float* __restrict__ h,
                                                  const int* __restrict__ gstart,
                                                  const float* __restrict__ Wc1,
                                                  const float* __restrict__ bc1,
                                                  const float* __restrict__ Wc2,
                                                  const float* __restrict__ bc2,
                                                  float* __restrict__ outp, int n) {
    const int g = blockIdx.x;
    const int lo = gstart[g], lo2 = gstart[g + 1];
    const int t = threadIdx.x;
    const int rg = t >> 4;
    const int c4 = (t & 15) * 4;
    float4 acc = make_float4(0.f, 0.f, 0.f, 0.f);
    for (int r = lo + rg; r < lo2; r += 32) {
        float4 v = *(const float4*)(h + (size_t)r * HID + c4);
        acc.x += v.x; acc.y += v.y; acc.z += v.z; acc.w += v.w;
    }
    __shared__ float4 red[32][16];
    __shared__ float gmv[HID];
    __shared__ float zs[32];
    red[rg][t & 15] = acc;
    __syncthreads();
    if (t < 16) {
        float4 s = red[0][t];
#pragma unroll
        for (int g2 = 1; g2 < 32; ++g2) {
            float4 v = red[g2][t];
            s.x += v.x; s.y += v.y; s.z += v.z; s.w += v.w;
        }
        float inv = 1.0f / fmaxf((float)(lo2 - lo), 1.0f);
        gmv[t * 4 + 0] = s.x * inv; gmv[t * 4 + 1] = s.y * inv;
        gmv[t * 4 + 2] = s.z * inv; gmv[t * 4 + 3] = s.w * inv;
    }
    __syncthreads();
    if (t < 32) {
        float z = bc1[t];
#pragma unroll 8
        for (int k = 0; k < HID; ++k) z = fmaf(gmv[k], Wc1[k * 32 + t], z);
        zs[t] = fmaxf(z, 0.f) * Wc2[t];
    }
    __syncthreads();
    if (t == 0) {
        float o = bc2[0];
#pragma unroll
        for (int j = 0; j < 32; ++j) o += zs[j];
        outp[g] = o;
    }
}

extern "C" void kernel_launch(void* const* d_in, const int* in_sizes, int n_in,
                              void* d_out, int out_size, void* d_ws, size_t ws_size,
                              hipStream_t stream) {
    const float* x    = (const float*)d_in[0];
    const int*   ei   = (const int*)d_in[1];
    const int*   batch= (const int*)d_in[2];
    const float* W1   = (const float*)d_in[3];
    const float* b1   = (const float*)d_in[4];
    const float* W2   = (const float*)d_in[5];
    const float* b2   = (const float*)d_in[6];
    const float* Wc1  = (const float*)d_in[7];
    const float* bc1  = (const float*)d_in[8];
    const float* Wc2  = (const float*)d_in[9];
    const float* bc2  = (const float*)d_in[10];

    const int E = in_sizes[1] / 2;
    const int n = in_sizes[0] / 128;   // 50000 nodes
    const int* srcp = ei;
    const int* dstp = ei + E;

    char* ws = (char*)d_ws;
    auto alloc = [&](size_t bytes) {
        char* p = ws;
        ws += (bytes + 255) & ~(size_t)255;
        return p;
    };
    int*   deg      = (int*)  alloc((size_t)((n + 3) & ~3) * 4);
    float* dinv     = (float*)alloc((size_t)n * 4);
    int*   gstart   = (int*)  alloc((size_t)(NG + 1) * 4);
    int*   col_ell  = (int*)  alloc((size_t)n * ELL * 4);
    float* bufA     = (float*)alloc((size_t)n * HID * 4);
    float* bufB     = (float*)alloc((size_t)n * HID * 4);
    unsigned short* W1hi = (unsigned short*)alloc(128 * 64 * 2);
    unsigned short* W1lo = (unsigned short*)alloc(128 * 64 * 2);
    unsigned short* W2hi = (unsigned short*)alloc(64 * 64 * 2);
    unsigned short* W2lo = (unsigned short*)alloc(64 * 64 * 2);

    const int n4 = (n + 3) / 4;
    const int prepblk = (max(n4, 128 * 64 + 64 * 64) + 255) / 256;
    k_prep<<<prepblk, 256, 0, stream>>>((int4*)deg, n4, W1, W2,
                                        W1hi, W1lo, W2hi, W2lo);

    const int nbin = (E + 255) / 256;
    const int mblocks = ((n + 31) / 32 + 3) / 4;
    const int nblk = (n + 255) / 256;

    // MEGA: degfill + gemm1(unscaled) + gstart
    k_mega<<<nbin + mblocks + nblk, 256, 0, stream>>>(srcp, dstp, E, deg, col_ell,
                                                      x, W1hi, W1lo, bufA,
                                                      batch, gstart, n, nbin, mblocks);

    k_dinv<<<nblk, 256, 0, stream>>>(deg, dinv, n);

    // Fused {gather1 (per-edge dinv) + gemm2 (output pre-scaled)}, then gather2
    k_gather_gemm2<<<(n + 31) / 32, 512, 0, stream>>>(bufA, deg, col_ell, dinv, b1,
                                                      W2hi, W2lo, bufB, n);
    k_gather<<<(n + 15) / 16, 256, 0, stream>>>(bufB, deg, col_ell, dinv, b2, bufA, n);

    // Fused pool + head
    k_poolhead<<<NG, 512, 0, stream>>>(bufA, gstart, Wc1, bc1, Wc2, bc2, (float*)d_out, n);
}

// Round 16
// 153.056 us; speedup vs baseline: 1.1682x; 1.0567x over previous
//
#include <hip/hip_runtime.h>
#include <math.h>

#define NG 64
#define HID 64
#define ELL 64     // slots per node; P(deg>64)~1e-19 for Poisson(16)
#define NSCAN 16   // dst-range groups for the temporally-clustered scatter

typedef __attribute__((ext_vector_type(8))) short bf16x8;
typedef __attribute__((ext_vector_type(4))) float f32x4;

// RNE f32 -> bf16 bit helpers (data finite; no NaN handling needed)
__device__ __forceinline__ unsigned int bfbits(float f) {
    unsigned int u = __float_as_uint(f);
    return (u + 0x7FFFu + ((u >> 16) & 1u)) >> 16;
}
__device__ __forceinline__ float bfval(unsigned int bits) {
    return __uint_as_float(bits << 16);
}
__device__ __forceinline__ float dinv_of(int d) {
    return 1.0f / sqrtf((float)d + 1.0f);
}

// ---- prep: zero deg + gstart (sorted batch boundaries) + W pre-split ----
__global__ __launch_bounds__(256) void k_prep(int* __restrict__ deg, int n,
                                              const int* __restrict__ batch,
                                              int* __restrict__ gstart,
                                              const float* __restrict__ W1,
                                              const float* __restrict__ W2,
                                              unsigned short* __restrict__ W1hi,
                                              unsigned short* __restrict__ W1lo,
                                              unsigned short* __restrict__ W2hi,
                                              unsigned short* __restrict__ W2lo) {
    int i = blockIdx.x * 256 + threadIdx.x;
    if (i < n) {
        deg[i] = 0;
        int bi = batch[i];
        int bp = (i == 0) ? -1 : batch[i - 1];
        for (int g = bp + 1; g <= bi; ++g) gstart[g] = i;
        if (i == n - 1)
            for (int g = bi + 1; g <= NG; ++g) gstart[g] = n;
    }
    if (i < 128 * 64) {
        int k = i >> 6, c = i & 63;
        float f = W1[i];
        unsigned hb = bfbits(f);
        W1hi[c * 128 + k] = (unsigned short)hb;
        W1lo[c * 128 + k] = (unsigned short)bfbits(f - bfval(hb));
    }
    int i2 = i - 128 * 64;
    if (i2 >= 0 && i2 < 64 * 64) {
        int k = i2 >> 6, c = i2 & 63;
        float f = W2[i2];
        unsigned hb = bfbits(f);
        W2hi[c * 64 + k] = (unsigned short)hb;
        W2lo[c * 64 + k] = (unsigned short)bfbits(f - bfval(hb));
    }
}

// ---- ELL build, range-clustered: group r scatters only dst in range r.
// Blocks dispatch roughly in order -> ~2-3 active ranges (~2MB write window)
// -> a node's ~16 slot-writes combine in L2 before writeback. Any block
// order remains CORRECT (atomics + filter are order-independent).
__global__ __launch_bounds__(256) void k_degfill(const int* __restrict__ src,
                                                 const int* __restrict__ dst, int E,
                                                 int step, int n,
                                                 int* __restrict__ deg,
                                                 int* __restrict__ col_ell, int bpg) {
    const int group = blockIdx.x / bpg;
    const int blk   = blockIdx.x % bpg;
    const int lo = group * step;
    const int hi = min(lo + step, n);
    const int base = blk * 1024;
#pragma unroll
    for (int k = 0; k < 4; ++k) {
        int e = base + k * 256 + threadIdx.x;
        if (e < E) {
            int d = dst[e];
            if (d >= lo && d < hi) {
                int slot = atomicAdd(deg + d, 1);
                if (slot < ELL) col_ell[(size_t)d * ELL + slot] = src[e];
            }
        }
    }
}

// ---- MFMA GEMM (layer 1): out = (A[n,128] @ W) * dinv[row], 32 rows/wave ----
template<int K>
__global__ __launch_bounds__(256) void k_gemm_mfma(const float* __restrict__ A,
                                                   const unsigned short* __restrict__ Whi,
                                                   const unsigned short* __restrict__ Wlo,
                                                   const int* __restrict__ deg,
                                                   float* __restrict__ out, int n) {
    const int wave = threadIdx.x >> 6, lane = threadIdx.x & 63;
    const int ntile2 = (n + 31) >> 5;
    const int tile2 = blockIdx.x * 4 + wave;
    if (tile2 >= ntile2) return;
    const int lrow = lane & 15;
    const int kgrp = lane >> 4;
    const int r0 = tile2 * 32 + lrow;
    const int r1 = r0 + 16;

    f32x4 acc0[4], acc1[4];
#pragma unroll
    for (int ct = 0; ct < 4; ++ct) {
        acc0[ct] = (f32x4){0.f, 0.f, 0.f, 0.f};
        acc1[ct] = (f32x4){0.f, 0.f, 0.f, 0.f};
    }

#pragma unroll
    for (int s = 0; s < K / 32; ++s) {
        float a0[8], a1[8];
        {
            const float* p0 = A + (size_t)r0 * K + s * 32 + kgrp * 8;
            const float* p1 = A + (size_t)r1 * K + s * 32 + kgrp * 8;
            float4 u0, u1, w0, w1;
            if (r0 < n) { u0 = *(const float4*)p0; u1 = *(const float4*)(p0 + 4); }
            else { u0 = make_float4(0.f,0.f,0.f,0.f); u1 = u0; }
            if (r1 < n) { w0 = *(const float4*)p1; w1 = *(const float4*)(p1 + 4); }
            else { w0 = make_float4(0.f,0.f,0.f,0.f); w1 = w0; }
            a0[0]=u0.x; a0[1]=u0.y; a0[2]=u0.z; a0[3]=u0.w;
            a0[4]=u1.x; a0[5]=u1.y; a0[6]=u1.z; a0[7]=u1.w;
            a1[0]=w0.x; a1[1]=w0.y; a1[2]=w0.z; a1[3]=w0.w;
            a1[4]=w1.x; a1[5]=w1.y; a1[6]=w1.z; a1[7]=w1.w;
        }
        bf16x8 ahi0, alo0, ahi1, alo1;
#pragma unroll
        for (int e = 0; e < 8; ++e) {
            unsigned hb0 = bfbits(a0[e]);
            ahi0[e] = (short)hb0;
            alo0[e] = (short)bfbits(a0[e] - bfval(hb0));
            unsigned hb1 = bfbits(a1[e]);
            ahi1[e] = (short)hb1;
            alo1[e] = (short)bfbits(a1[e] - bfval(hb1));
        }
#pragma unroll
        for (int ct = 0; ct < 4; ++ct) {
            const size_t wo = (size_t)(ct * 16 + lrow) * K + s * 32 + kgrp * 8;
            bf16x8 whi = *(const bf16x8*)(Whi + wo);
            bf16x8 wlo = *(const bf16x8*)(Wlo + wo);
            acc0[ct] = __builtin_amdgcn_mfma_f32_16x16x32_bf16(ahi0, whi, acc0[ct], 0, 0, 0);
            acc0[ct] = __builtin_amdgcn_mfma_f32_16x16x32_bf16(alo0, whi, acc0[ct], 0, 0, 0);
            acc0[ct] = __builtin_amdgcn_mfma_f32_16x16x32_bf16(ahi0, wlo, acc0[ct], 0, 0, 0);
            acc1[ct] = __builtin_amdgcn_mfma_f32_16x16x32_bf16(ahi1, whi, acc1[ct], 0, 0, 0);
            acc1[ct] = __builtin_amdgcn_mfma_f32_16x16x32_bf16(alo1, whi, acc1[ct], 0, 0, 0);
            acc1[ct] = __builtin_amdgcn_mfma_f32_16x16x32_bf16(ahi1, wlo, acc1[ct], 0, 0, 0);
        }
    }

#pragma unroll
    for (int r = 0; r < 4; ++r) {
        int o0 = tile2 * 32 + kgrp * 4 + r;
        if (o0 < n) {
            float dv = dinv_of(deg[o0]);
#pragma unroll
            for (int ct = 0; ct < 4; ++ct)
                out[(size_t)o0 * HID + ct * 16 + lrow] = acc0[ct][r] * dv;
        }
        int o1 = o0 + 16;
        if (o1 < n) {
            float dv = dinv_of(deg[o1]);
#pragma unroll
            for (int ct = 0; ct < 4; ++ct)
                out[(size_t)o1 * HID + ct * 16 + lrow] = acc1[ct][r] * dv;
        }
    }
}

// ---- FUSED: lane-group ELL gather (hs pre-scaled by dinv) + gemm2 (MFMA) ----
__global__ __launch_bounds__(512) void k_gather_gemm2(const float* __restrict__ hs,
                                                      const int* __restrict__ deg,
                                                      const int* __restrict__ col_ell,
                                                      const float* __restrict__ bias,
                                                      const unsigned short* __restrict__ Whi,
                                                      const unsigned short* __restrict__ Wlo,
                                                      float* __restrict__ outB, int n) {
    __shared__ float Ash[32][68];  // +4 pad for MFMA-phase b128 reads
    const int wave = threadIdx.x >> 6, lane = threadIdx.x & 63;
    const int grp = lane >> 4, sub = lane & 15;
    const int row = wave * 4 + grp;
    const int node = blockIdx.x * 32 + row;
    const bool has = node < n;

    float4 acc = make_float4(0.f, 0.f, 0.f, 0.f);
    float di = 0.f;
    int j = 0, e = 0;
    const int* cbase = col_ell + (size_t)node * ELL;
    if (has) {
        int dg = deg[node];
        e = min(dg, ELL);
        di = dinv_of(dg);
        acc = *(const float4*)(hs + (size_t)node * HID + sub * 4);
    }
    while (__any(j < e)) {
        int cc[8];
#pragma unroll
        for (int t = 0; t < 8; ++t) cc[t] = (j + t < e) ? cbase[j + t] : -1;
        float4 vv[8];
#pragma unroll
        for (int t = 0; t < 8; ++t)
            if (cc[t] >= 0) vv[t] = *(const float4*)(hs + (size_t)cc[t] * HID + sub * 4);
#pragma unroll
        for (int t = 0; t < 8; ++t)
            if (cc[t] >= 0) {
                acc.x += vv[t].x; acc.y += vv[t].y;
                acc.z += vv[t].z; acc.w += vv[t].w;
            }
        j += 8;
    }
    {
        float4 bv = *(const float4*)(bias + sub * 4);
        float4 o;
        o.x = has ? fmaxf(fmaf(acc.x, di, bv.x), 0.f) : 0.f;
        o.y = has ? fmaxf(fmaf(acc.y, di, bv.y), 0.f) : 0.f;
        o.z = has ? fmaxf(fmaf(acc.z, di, bv.z), 0.f) : 0.f;
        o.w = has ? fmaxf(fmaf(acc.w, di, bv.w), 0.f) : 0.f;
        *(float4*)&Ash[row][sub * 4] = o;
    }
    __syncthreads();

    // gemm phase (K=64): 8 units (2 rowtiles x 4 coltiles), 1 per wave;
    // output pre-scaled by dinv so gather2 runs the cheap pre-scaled form.
    const int rt = wave >> 2, ct = wave & 3;
    const int lrow = lane & 15;
    const int kgrp = lane >> 4;
    f32x4 a = (f32x4){0.f, 0.f, 0.f, 0.f};
#pragma unroll
    for (int s = 0; s < 2; ++s) {
        const float* ap = &Ash[rt * 16 + lrow][s * 32 + kgrp * 8];
        float4 u0 = *(const float4*)ap;
        float4 u1 = *(const float4*)(ap + 4);
        float av[8] = {u0.x, u0.y, u0.z, u0.w, u1.x, u1.y, u1.z, u1.w};
        bf16x8 ahi, alo;
#pragma unroll
        for (int e2 = 0; e2 < 8; ++e2) {
            unsigned hb = bfbits(av[e2]);
            ahi[e2] = (short)hb;
            alo[e2] = (short)bfbits(av[e2] - bfval(hb));
        }
        const size_t wo = (size_t)(ct * 16 + lrow) * 64 + s * 32 + kgrp * 8;
        bf16x8 whi = *(const bf16x8*)(Whi + wo);
        bf16x8 wlo = *(const bf16x8*)(Wlo + wo);
        a = __builtin_amdgcn_mfma_f32_16x16x32_bf16(ahi, whi, a, 0, 0, 0);
        a = __builtin_amdgcn_mfma_f32_16x16x32_bf16(alo, whi, a, 0, 0, 0);
        a = __builtin_amdgcn_mfma_f32_16x16x32_bf16(ahi, wlo, a, 0, 0, 0);
    }
#pragma unroll
    for (int r = 0; r < 4; ++r) {
        int orow = blockIdx.x * 32 + rt * 16 + kgrp * 4 + r;
        if (orow < n)
            outB[(size_t)orow * HID + ct * 16 + lrow] = a[r] * dinv_of(deg[orow]);
    }
}

// ---- lane-group ELL gather (layer 2, hs pre-scaled), direct store ----
__global__ __launch_bounds__(256) void k_gather(const float* __restrict__ hs,
                                                const int* __restrict__ deg,
                                                const int* __restrict__ col_ell,
                                                const float* __restrict__ bias,
                                                float* __restrict__ out, int n) {
    const int wave = threadIdx.x >> 6, lane = threadIdx.x & 63;
    const int grp = lane >> 4, sub = lane & 15;
    const int node = blockIdx.x * 16 + wave * 4 + grp;
    const bool has = node < n;

    float4 acc = make_float4(0.f, 0.f, 0.f, 0.f);
    float di = 0.f;
    int j = 0, e = 0;
    const int* cbase = col_ell + (size_t)node * ELL;
    if (has) {
        int dg = deg[node];
        e = min(dg, ELL);
        di = dinv_of(dg);
        acc = *(const float4*)(hs + (size_t)node * HID + sub * 4);
    }
    while (__any(j < e)) {
        int cc[8];
#pragma unroll
        for (int t = 0; t < 8; ++t) cc[t] = (j + t < e) ? cbase[j + t] : -1;
        float4 vv[8];
#pragma unroll
        for (int t = 0; t < 8; ++t)
            if (cc[t] >= 0) vv[t] = *(const float4*)(hs + (size_t)cc[t] * HID + sub * 4);
#pragma unroll
        for (int t = 0; t < 8; ++t)
            if (cc[t] >= 0) {
                acc.x += vv[t].x; acc.y += vv[t].y;
                acc.z += vv[t].z; acc.w += vv[t].w;
            }
        j += 8;
    }
    if (has) {
        float4 bv = *(const float4*)(bias + sub * 4);
        float4 o;
        o.x = fmaxf(fmaf(acc.x, di, bv.x), 0.f);
        o.y = fmaxf(fmaf(acc.y, di, bv.y), 0.f);
        o.z = fmaxf(fmaf(acc.z, di, bv.z), 0.f);
        o.w = fmaxf(fmaf(acc.w, di, bv.w), 0.f);
        *(float4*)(out + (size_t)node * HID + sub * 4) = o;
    }
}

// ---- fused mean-pool + MLP head ----
__global__ __launch_bounds__(512) void k_poolhead(const float* __restrict__ h,
                                                  const int* __restrict__ gstart,
                                                  const float* __restrict__ Wc1,
                                                  const float* __restrict__ bc1,
                                                  const float* __restrict__ Wc2,
                                                  const float* __restrict__ bc2,
                                                  float* __restrict__ outp, int n) {
    const int g = blockIdx.x;
    const int lo = gstart[g], lo2 = gstart[g + 1];
    const int t = threadIdx.x;
    const int rg = t >> 4;
    const int c4 = (t & 15) * 4;
    float4 acc = make_float4(0.f, 0.f, 0.f, 0.f);
    for (int r = lo + rg; r < lo2; r += 32) {
        float4 v = *(const float4*)(h + (size_t)r * HID + c4);
        acc.x += v.x; acc.y += v.y; acc.z += v.z; acc.w += v.w;
    }
    __shared__ float4 red[32][16];
    __shared__ float gmv[HID];
    __shared__ float zs[32];
    red[rg][t & 15] = acc;
    __syncthreads();
    if (t < 16) {
        float4 s = red[0][t];
#pragma unroll
        for (int g2 = 1; g2 < 32; ++g2) {
            float4 v = red[g2][t];
            s.x += v.x; s.y += v.y; s.z += v.z; s.w += v.w;
        }
        float inv = 1.0f / fmaxf((float)(lo2 - lo), 1.0f);
        gmv[t * 4 + 0] = s.x * inv; gmv[t * 4 + 1] = s.y * inv;
        gmv[t * 4 + 2] = s.z * inv; gmv[t * 4 + 3] = s.w * inv;
    }
    __syncthreads();
    if (t < 32) {
        float z = bc1[t];
#pragma unroll 8
        for (int k = 0; k < HID; ++k) z = fmaf(gmv[k], Wc1[k * 32 + t], z);
        zs[t] = fmaxf(z, 0.f) * Wc2[t];
    }
    __syncthreads();
    if (t == 0) {
        float o = bc2[0];
#pragma unroll
        for (int j = 0; j < 32; ++j) o += zs[j];
        outp[g] = o;
    }
}

extern "C" void kernel_launch(void* const* d_in, const int* in_sizes, int n_in,
                              void* d_out, int out_size, void* d_ws, size_t ws_size,
                              hipStream_t stream) {
    const float* x    = (const float*)d_in[0];
    const int*   ei   = (const int*)d_in[1];
    const int*   batch= (const int*)d_in[2];
    const float* W1   = (const float*)d_in[3];
    const float* b1   = (const float*)d_in[4];
    const float* W2   = (const float*)d_in[5];
    const float* b2   = (const float*)d_in[6];
    const float* Wc1  = (const float*)d_in[7];
    const float* bc1  = (const float*)d_in[8];
    const float* Wc2  = (const float*)d_in[9];
    const float* bc2  = (const float*)d_in[10];

    const int E = in_sizes[1] / 2;
    const int n = in_sizes[0] / 128;   // 50000 nodes
    const int* srcp = ei;
    const int* dstp = ei + E;

    char* ws = (char*)d_ws;
    auto alloc = [&](size_t bytes) {
        char* p = ws;
        ws += (bytes + 255) & ~(size_t)255;
        return p;
    };
    int*   deg      = (int*)  alloc((size_t)n * 4);
    int*   gstart   = (int*)  alloc((size_t)(NG + 1) * 4);
    int*   col_ell  = (int*)  alloc((size_t)n * ELL * 4);
    float* bufA     = (float*)alloc((size_t)n * HID * 4);
    float* bufB     = (float*)alloc((size_t)n * HID * 4);
    unsigned short* W1hi = (unsigned short*)alloc(128 * 64 * 2);
    unsigned short* W1lo = (unsigned short*)alloc(128 * 64 * 2);
    unsigned short* W2hi = (unsigned short*)alloc(64 * 64 * 2);
    unsigned short* W2lo = (unsigned short*)alloc(64 * 64 * 2);

    const int nblk = (n + 255) / 256;
    k_prep<<<nblk, 256, 0, stream>>>(deg, n, batch, gstart,
                                     W1, W2, W1hi, W1lo, W2hi, W2lo);

    // range-clustered ELL build: NSCAN groups, each scans all edges,
    // scatters only its dst-range (write window fits per-XCD L2)
    const int bpg = (E + 1023) / 1024;
    const int step = (n + NSCAN - 1) / NSCAN;
    k_degfill<<<NSCAN * bpg, 256, 0, stream>>>(srcp, dstp, E, step, n,
                                               deg, col_ell, bpg);

    const int mblocks = ((n + 31) / 32 + 3) / 4;

    // Layer 1 GEMM (dinv from deg inline), fused {gather1 + gemm2}, gather2
    k_gemm_mfma<128><<<mblocks, 256, 0, stream>>>(x, W1hi, W1lo, deg, bufA, n);
    k_gather_gemm2<<<(n + 31) / 32, 512, 0, stream>>>(bufA, deg, col_ell, b1,
                                                      W2hi, W2lo, bufB, n);
    k_gather<<<(n + 15) / 16, 256, 0, stream>>>(bufB, deg, col_ell, b2, bufA, n);

    // Fused pool + head
    k_poolhead<<<NG, 512, 0, stream>>>(bufA, gstart, Wc1, bc1, Wc2, bc2, (float*)d_out, n);
}